// Round 14
// baseline (233.210 us; speedup 1.0000x reference)
//
#include <hip/hip_runtime.h>

// CQAttention fused pipeline for MI355X (gfx950).
// B=32, D=256, Lc=2048, Lq=256, fp32 in/out, bf16 MFMA internally.
// R14 = R13/R9 + k3/Up path rework: KSPLIT 4->8 (4 blocks/CU), bf16 partials
// in a slot-indexed coalesced layout (512B/wave stores; same 33.5MB bytes),
// k3r re-geometried to match. k1/k2/k4/qprep unchanged. Workspace ~105 MB.

#define B_ 32
#define D_ 256
#define LC 2048
#define LQ 256
#define KSPLIT 8
#define NEG_INF (-1e30f)

using bf16   = __bf16;
using bf16x4 = __attribute__((ext_vector_type(4))) __bf16;
using bf16x8 = __attribute__((ext_vector_type(8))) __bf16;
using f32x4  = __attribute__((ext_vector_type(4))) float;

static __device__ __forceinline__ f32x4 mfma16(bf16x8 a, bf16x8 b, f32x4 c) {
  return __builtin_amdgcn_mfma_f32_16x16x32_bf16(a, b, c, 0, 0, 0);
}
static __device__ __forceinline__ void nt_store4(float* p, f32x4 v) {
  __builtin_nontemporal_store(v, (f32x4*)p);
}

// ---------------------------------------------------------------------------
// K0a: transpose Q (b,d,q) f32 -> Qtb (b,q,d) bf16; cast Qb16[b][d][q];
// and per-(dt,q) partial dots bqp[b][dt][q] = sum_{d in dt} Q[d][q]*w2[d].
// ---------------------------------------------------------------------------
__global__ __launch_bounds__(256) void qprep(const float* __restrict__ Q,
                                             const float* __restrict__ w,
                                             bf16* __restrict__ Qtb,
                                             bf16* __restrict__ Qb16,
                                             float* __restrict__ bqp) {
  __shared__ float t[64][65];
  __shared__ float pb[4][64];
  const int b  = blockIdx.y;
  const int qt = (blockIdx.x >> 2) * 64;
  const int dtI = blockIdx.x & 3, dt = dtI * 64;
  const int c  = threadIdx.x & 63, r0 = threadIdx.x >> 6;
  const float* Qb = Q + (size_t)b * D_ * LQ;
  bf16* Qcb = Qb16 + (size_t)b * D_ * LQ;
  float partial = 0.f;
#pragma unroll
  for (int r = r0; r < 64; r += 4) {
    const float v = Qb[(size_t)(dt + r) * LQ + qt + c];
    t[r][c] = v;
    Qcb[(size_t)(dt + r) * LQ + qt + c] = (bf16)v;
    partial += v * w[D_ + dt + r];
  }
  pb[r0][c] = partial;
  __syncthreads();
  bf16* O = Qtb + (size_t)b * LQ * D_;
#pragma unroll
  for (int r = r0; r < 64; r += 4)
    O[(size_t)(qt + r) * D_ + dt + c] = (bf16)t[c][r];  // Qtb[q][d] = Q[d][q]
  if (r0 == 0)
    bqp[((size_t)(b * 4 + dtI)) * LQ + qt + c] = pb[0][c] + pb[1][c] + pb[2][c] + pb[3][c];
}

// ---------------------------------------------------------------------------
// K1: S = (C*w3)^T @ Q + a[c] + bq[q], rounded to bf16.
// R6 LDS staging + T14 register prefetch. S1 AND S1t written via LDS bounce.
// ---------------------------------------------------------------------------
__global__ __launch_bounds__(256) void k1_sgemm(
    const float* __restrict__ C, const bf16* __restrict__ Qtb,
    const float* __restrict__ w, const float* __restrict__ cmask,
    const float* __restrict__ qmask, const float* __restrict__ bqp,
    bf16* __restrict__ S1, bf16* __restrict__ S1t,
    float* __restrict__ cpmax, float* __restrict__ cpsum) {
  __shared__ union __align__(16) SmU {
    struct { bf16 As[64][72]; bf16 Bs[256][72]; } st;  // K-loop (46.1 KB)
    bf16 tb[256][72];                                   // S1t bounce
    bf16 sb[64][264];                                   // S1 bounce
  } smu;
  __shared__ float ared[4][64];
  __shared__ float wred[4][64];
  __shared__ float wsum[4][64];
  __shared__ float cml[64];
  __shared__ float qml[256];
  __shared__ float bql[256];

  const int b = blockIdx.y, ct = blockIdx.x, c0 = ct * 64;
  const int tid = threadIdx.x, lane = tid & 63, wv = tid >> 6;
  const float* Cb = C + (size_t)b * D_ * LC;
  const bf16* Qt = Qtb + (size_t)b * LQ * D_;
  const float* w1 = w;
  const float* w3 = w + 2 * D_;

  if (tid < 64) cml[tid] = cmask[b * LC + c0 + tid];
  qml[tid] = qmask[b * LQ + tid];
  bql[tid] = bqp[(size_t)(b * 4 + 0) * LQ + tid] + bqp[(size_t)(b * 4 + 1) * LQ + tid] +
             bqp[(size_t)(b * 4 + 2) * LQ + tid] + bqp[(size_t)(b * 4 + 3) * LQ + tid];

  f32x4 acc[4][4];
#pragma unroll
  for (int i = 0; i < 4; i++)
#pragma unroll
    for (int j = 0; j < 4; j++) acc[i][j] = {0.f, 0.f, 0.f, 0.f};
  float acc_a = 0.f;

  const int sm = tid & 63;   // staging: m (c)
  const int skg = tid >> 6;  // staging: k-group

  // ---- prologue: prefetch tile 0 into registers ----
  float aPre[16];
  bf16x8 bPre[8];
#pragma unroll
  for (int i = 0; i < 16; ++i)
    aPre[i] = Cb[(size_t)(skg * 16 + i) * LC + c0 + sm];
#pragma unroll
  for (int p = 0; p < 8; ++p) {
    const int idx = (p * 256 + tid) * 8;
    bPre[p] = *(const bf16x8*)(Qt + (size_t)(idx >> 6) * D_ + (idx & 63));
  }

  for (int it = 0; it < 4; ++it) {
    const int k0 = it * 64;
#pragma unroll
    for (int i = 0; i < 16; ++i) {
      const int k = skg * 16 + i, kgl = k0 + k;
      smu.st.As[sm][k] = (bf16)(aPre[i] * w3[kgl]);
      acc_a += aPre[i] * w1[kgl];
    }
#pragma unroll
    for (int p = 0; p < 8; ++p) {
      const int idx = (p * 256 + tid) * 8;
      *(bf16x8*)(&smu.st.Bs[idx >> 6][idx & 63]) = bPre[p];
    }
    __syncthreads();
    // T14: next tile's global loads issued now; complete under the MFMAs
    if (it < 3) {
#pragma unroll
      for (int i = 0; i < 16; ++i)
        aPre[i] = Cb[(size_t)(k0 + 64 + skg * 16 + i) * LC + c0 + sm];
#pragma unroll
      for (int p = 0; p < 8; ++p) {
        const int idx = (p * 256 + tid) * 8;
        bPre[p] = *(const bf16x8*)(Qt + (size_t)(idx >> 6) * D_ + k0 + 64 + (idx & 63));
      }
    }
#pragma unroll
    for (int kk = 0; kk < 64; kk += 32) {
      bf16x8 af[4], bfr[4];
#pragma unroll
      for (int mi = 0; mi < 4; mi++)
        af[mi] = *(const bf16x8*)(&smu.st.As[mi * 16 + (lane & 15)][kk + (lane >> 4) * 8]);
#pragma unroll
      for (int ni = 0; ni < 4; ni++)
        bfr[ni] = *(const bf16x8*)(&smu.st.Bs[wv * 64 + ni * 16 + (lane & 15)][kk + (lane >> 4) * 8]);
#pragma unroll
      for (int mi = 0; mi < 4; mi++)
#pragma unroll
        for (int ni = 0; ni < 4; ni++)
          acc[mi][ni] = mfma16(af[mi], bfr[ni], acc[mi][ni]);
    }
    __syncthreads();
  }

  ared[skg][sm] = acc_a;
  __syncthreads();

  const int r4 = (lane >> 4) * 4;  // fragment row base
  const int cn = lane & 15;        // fragment col

  // acc <- raw S rounded to bf16 (kept as floats of rounded values)
#pragma unroll
  for (int mi = 0; mi < 4; mi++)
#pragma unroll
    for (int j = 0; j < 4; j++) {
      const int m = mi * 16 + r4 + j;
      const float aval = ared[0][m] + ared[1][m] + ared[2][m] + ared[3][m];
#pragma unroll
      for (int ni = 0; ni < 4; ni++) {
        const int n = wv * 64 + ni * 16 + cn;
        const bf16 sb = (bf16)(acc[mi][ni][j] + aval + bql[n]);
        acc[mi][ni][j] = (float)sb;
      }
    }

  // ---- column partial stats (cmask logits, raw acc) ----
#pragma unroll
  for (int ni = 0; ni < 4; ni++) {
    const int n = wv * 64 + ni * 16 + cn;
    float mx = -3.0e38f;
#pragma unroll
    for (int mi = 0; mi < 4; mi++)
#pragma unroll
      for (int j = 0; j < 4; j++) {
        const int m = mi * 16 + r4 + j;
        const float cmv = cml[m];
        const float lg = acc[mi][ni][j] * cmv + (1.f - cmv) * NEG_INF;
        mx = fmaxf(mx, lg);
      }
    mx = fmaxf(mx, __shfl_xor(mx, 16));
    mx = fmaxf(mx, __shfl_xor(mx, 32));
    float ps = 0.f;
#pragma unroll
    for (int mi = 0; mi < 4; mi++)
#pragma unroll
      for (int j = 0; j < 4; j++) {
        const int m = mi * 16 + r4 + j;
        const float cmv = cml[m];
        const float lg = acc[mi][ni][j] * cmv + (1.f - cmv) * NEG_INF;
        ps += __expf(lg - mx);
      }
    ps += __shfl_xor(ps, 16);
    ps += __shfl_xor(ps, 32);
    if ((lane >> 4) == 0) {
      cpmax[((size_t)(b * 32 + ct)) * LQ + n] = mx;
      cpsum[((size_t)(b * 32 + ct)) * LQ + n] = ps;
    }
  }

  // ---- row max (qmask logits) ----
#pragma unroll
  for (int mi = 0; mi < 4; mi++)
#pragma unroll
    for (int j = 0; j < 4; j++) {
      float mx = -3.0e38f;
#pragma unroll
      for (int ni = 0; ni < 4; ni++) {
        const int n = wv * 64 + ni * 16 + cn;
        const float qm = qml[n];
        const float lg = acc[mi][ni][j] * qm + (1.f - qm) * NEG_INF;
        mx = fmaxf(mx, lg);
      }
      for (int s = 1; s < 16; s <<= 1) mx = fmaxf(mx, __shfl_xor(mx, s));
      if (cn == 0) wred[wv][mi * 16 + r4 + j] = mx;
    }
  __syncthreads();

  // ---- e = exp(lg - rm) overwrites acc; row sums ----
  float rmv[4][4];
#pragma unroll
  for (int mi = 0; mi < 4; mi++)
#pragma unroll
    for (int j = 0; j < 4; j++) {
      const int m = mi * 16 + r4 + j;
      const float rm = fmaxf(fmaxf(wred[0][m], wred[1][m]), fmaxf(wred[2][m], wred[3][m]));
      rmv[mi][j] = rm;
      float ps = 0.f;
#pragma unroll
      for (int ni = 0; ni < 4; ni++) {
        const int n = wv * 64 + ni * 16 + cn;
        const float qm = qml[n];
        const float lg = acc[mi][ni][j] * qm + (1.f - qm) * NEG_INF;
        const float e = __expf(lg - rm);
        acc[mi][ni][j] = e;
        ps += e;
      }
      for (int s = 1; s < 16; s <<= 1) ps += __shfl_xor(ps, s);
      if (cn == 0) wsum[wv][m] = ps;
    }
  __syncthreads();

  // ---- phase A: bounce S1t = bf16(e * cml * exp(rm)), flush coalesced ----
#pragma unroll
  for (int mi = 0; mi < 4; mi++)
#pragma unroll
    for (int j = 0; j < 4; j++) {
      const int m = mi * 16 + r4 + j;
      const float f = cml[m] * __expf(rmv[mi][j]);
#pragma unroll
      for (int ni = 0; ni < 4; ni++) {
        const int n = wv * 64 + ni * 16 + cn;
        smu.tb[n][m] = (bf16)(acc[mi][ni][j] * f);
      }
    }
  __syncthreads();
  {
    bf16* dst = S1t + ((size_t)b * LQ + tid) * LC + c0;
#pragma unroll
    for (int jj = 0; jj < 8; ++jj)
      *(bf16x8*)(dst + jj * 8) = *(const bf16x8*)(&smu.tb[tid][jj * 8]);
  }
  __syncthreads();

  // ---- phase B: bounce S1 = bf16(e * rsl), flush coalesced ----
#pragma unroll
  for (int mi = 0; mi < 4; mi++)
#pragma unroll
    for (int j = 0; j < 4; j++) {
      const int m = mi * 16 + r4 + j;
      const float rs = wsum[0][m] + wsum[1][m] + wsum[2][m] + wsum[3][m];
      const float rsl = 1.0f / rs;
#pragma unroll
      for (int ni = 0; ni < 4; ni++) {
        const int n = wv * 64 + ni * 16 + cn;
        smu.sb[m][n] = (bf16)(acc[mi][ni][j] * rsl);
      }
    }
  __syncthreads();
  {
    bf16* S1b = S1 + ((size_t)b * LC + c0) * LQ;
#pragma unroll
    for (int p = 0; p < 8; ++p) {
      const int flat = p * 2048 + tid * 8;
      *(bf16x8*)(S1b + flat) = *(const bf16x8*)(&smu.sb[flat >> 8][flat & 255]);
    }
  }
}

// ---------------------------------------------------------------------------
// K2: combine 32 column-partial stats -> cscl[b][q] = exp(-cmax)/csum.
// ---------------------------------------------------------------------------
__global__ __launch_bounds__(256) void k2_colstats(const float* __restrict__ cpmax,
                                                   const float* __restrict__ cpsum,
                                                   float* __restrict__ cscl) {
  const int b = blockIdx.x, q = threadIdx.x;
  float m = -3.0e38f;
  for (int t = 0; t < 32; t++) m = fmaxf(m, cpmax[(size_t)(b * 32 + t) * LQ + q]);
  float s = 0.f;
  for (int t = 0; t < 32; t++)
    s += cpsum[(size_t)(b * 32 + t) * LQ + q] * __expf(cpmax[(size_t)(b * 32 + t) * LQ + q] - m);
  cscl[b * LQ + q] = __expf(-m) / s;
}

// ---------------------------------------------------------------------------
// K3: Uraw[q,d] = sum_c S1t[q,c]*Ct[c,d] — 8-way split-K register GEMM.
// Partials stored as bf16 in a slot-indexed COALESCED layout:
//   region = (ks*B_+b)*4 + inner (inner = qt*2+dtI), 16384 bf16 per region;
//   offset = ((mi*4+ni)*256 + tid)*4  -> 512B contiguous per wave store.
// Grid 1024 blocks (4/CU). Quad-XCD swizzle retained.
// ---------------------------------------------------------------------------
__global__ __launch_bounds__(256, 4) void k3_ugemm(
    const bf16* __restrict__ S1t, const float* __restrict__ C,
    bf16* __restrict__ Up) {
  const int g = blockIdx.x;            // 0..1023
  const int x = g & 7, s = g >> 3;     // s: 0..127
  const int quad = (s >> 2) * 8 + x;   // 0..255 : (b, ks)
  const int inner = s & 3;             // (qt, dtI)
  const int b = quad >> 3, ks = quad & 7;
  const int qt = inner >> 1, dtI = inner & 1;
  const int mt = qt * 128, nt = dtI * 128;
  const int cbase = ks * (LC / KSPLIT);  // 256-wide K chunk

  const int tid = threadIdx.x, lane = tid & 63, wv = tid >> 6;
  const int wm = (wv >> 1) * 64, wn = (wv & 1) * 64;
  const int fr = lane & 15, kg = lane >> 4;

  const bf16* Sb = S1t + (size_t)b * LQ * LC;
  const float* Cb = C + (size_t)b * D_ * LC;

  int qrow[4];
#pragma unroll
  for (int mi = 0; mi < 4; mi++) qrow[mi] = mt + wm + mi * 16 + fr;

  f32x4 acc[4][4];
#pragma unroll
  for (int i = 0; i < 4; i++)
#pragma unroll
    for (int j = 0; j < 4; j++) acc[i][j] = {0.f, 0.f, 0.f, 0.f};

#pragma unroll 2
  for (int k0 = 0; k0 < LC / KSPLIT; k0 += 64) {
    const int c8 = cbase + k0 + kg * 8;
    bf16x8 af[4][2];
#pragma unroll
    for (int mi = 0; mi < 4; mi++)
#pragma unroll
      for (int s2 = 0; s2 < 2; ++s2)
        af[mi][s2] = *(const bf16x8*)(Sb + (size_t)qrow[mi] * LC + c8 + s2 * 32);
    bf16x8 bfr[4][2];
#pragma unroll
    for (int ni = 0; ni < 4; ni++) {
      const float* cp = Cb + (size_t)(nt + wn + ni * 16 + fr) * LC + c8;
#pragma unroll
      for (int s2 = 0; s2 < 2; ++s2) {
        const f32x4 v0 = *(const f32x4*)(cp + s2 * 32);
        const f32x4 v1 = *(const f32x4*)(cp + s2 * 32 + 4);
        bf16x8 tt;
#pragma unroll
        for (int e = 0; e < 4; ++e) { tt[e] = (bf16)v0[e]; tt[e + 4] = (bf16)v1[e]; }
        bfr[ni][s2] = tt;
      }
    }
#pragma unroll
    for (int s2 = 0; s2 < 2; ++s2)
#pragma unroll
      for (int mi = 0; mi < 4; mi++)
#pragma unroll
        for (int ni = 0; ni < 4; ni++)
          acc[mi][ni] = mfma16(af[mi][s2], bfr[ni][s2], acc[mi][ni]);
  }

  // slot-indexed coalesced bf16 partial store (512B contiguous per wave)
  bf16* UpB = Up + ((size_t)(ks * B_ + b) * 4 + inner) * 16384;
#pragma unroll
  for (int mi = 0; mi < 4; mi++)
#pragma unroll
    for (int ni = 0; ni < 4; ni++) {
      bf16x4 o = {(bf16)acc[mi][ni][0], (bf16)acc[mi][ni][1],
                  (bf16)acc[mi][ni][2], (bf16)acc[mi][ni][3]};
      __builtin_nontemporal_store(o, (bf16x4*)(UpB + ((mi * 4 + ni) * 256 + tid) * 4));
    }
}

// ---------------------------------------------------------------------------
// K3r: Utb[b][d][q] = bf16( cscl[b][q] * sum_ks Up_slot ). Geometry mirrors
// k3's thread mapping. Grid 2048 blocks: (b, inner, mi, ni).
// ---------------------------------------------------------------------------
__global__ __launch_bounds__(256) void k3r_reduce(const bf16* __restrict__ Up,
                                                  const float* __restrict__ cscl,
                                                  bf16* __restrict__ Utb) {
  const int g = blockIdx.x;           // 0..2047
  const int b = g >> 6, rest = g & 63;
  const int inner = rest >> 4, mn = rest & 15;
  const int mi = mn >> 2, ni = mn & 3;
  const int qt = inner >> 1, dtI = inner & 1;
  const int mt = qt * 128, nt = dtI * 128;

  const int tid = threadIdx.x, lane = tid & 63, wv = tid >> 6;
  const int wm = (wv >> 1) * 64, wn = (wv & 1) * 64;
  const int fr = lane & 15, kg = lane >> 4;

  const int q = mt + wm + mi * 16 + kg * 4;
  const int d = nt + wn + ni * 16 + fr;
  const int slot = ((mi * 4 + ni) * 256 + tid) * 4;

  float s0 = 0.f, s1 = 0.f, s2 = 0.f, s3 = 0.f;
#pragma unroll
  for (int ks = 0; ks < KSPLIT; ++ks) {
    const bf16x4 v = __builtin_nontemporal_load(
        (const bf16x4*)(Up + ((size_t)(ks * B_ + b) * 4 + inner) * 16384 + slot));
    s0 += (float)v[0]; s1 += (float)v[1]; s2 += (float)v[2]; s3 += (float)v[3];
  }
  const f32x4 sc = *(const f32x4*)(cscl + b * LQ + q);
  bf16x4 o = {(bf16)(s0 * sc[0]), (bf16)(s1 * sc[1]),
              (bf16)(s2 * sc[2]), (bf16)(s3 * sc[3])};
  *(bf16x4*)(Utb + (size_t)b * D_ * LQ + (size_t)d * LQ + q) = o;
}

// ---------------------------------------------------------------------------
// K4: A = S1 @ Qt, Bv = S1 @ U — k-outer register GEMM. Bounce epilogue
// (256B-contiguous stores per row), (256,3). Output non-temporal.
// ---------------------------------------------------------------------------
__global__ __launch_bounds__(256, 3) void k4_final(
    const bf16* __restrict__ S1, const float* __restrict__ C,
    const bf16* __restrict__ Qb16, const bf16* __restrict__ Utb,
    float* __restrict__ out) {
  __shared__ float bounce[64][131];

  const int g = blockIdx.x;            // 0..2047
  const int x = g & 7, s = g >> 3;     // s: 0..255
  const int t = s >> 1, ntI = s & 1;
  const int pair = t * 8 + x;          // 0..1023
  const int b = pair >> 5, ct = pair & 31;
  const int c0 = ct * 64, nt = ntI * 128;

  const int tid = threadIdx.x, lane = tid & 63, wv = tid >> 6;
  const int wm = (wv >> 1) * 32, wn = (wv & 1) * 64;
  const int fr = lane & 15, kg = lane >> 4;

  const bf16* S1b = S1 + ((size_t)b * LC + c0) * LQ;
  const float* Cb = C + (size_t)b * D_ * LC;
  const bf16* Qcb = Qb16 + (size_t)b * D_ * LQ;
  const bf16* Ub = Utb + (size_t)b * D_ * LQ;

  // ---- prefetch epilogue C tiles early (HBM latency under K-loop) ----
  const int cq = (tid & 15) * 4;    // 4 consecutive c per thread
  const int drb = tid >> 4;         // d-row base (0..15)
  f32x4 creg[8];
#pragma unroll
  for (int m = 0; m < 8; ++m)
    creg[m] = *(const f32x4*)(Cb + (size_t)(nt + drb + m * 16) * LC + c0 + cq);

  f32x4 acc1[2][4], acc2[2][4];
#pragma unroll
  for (int i = 0; i < 2; i++)
#pragma unroll
    for (int j = 0; j < 4; j++) {
      acc1[i][j] = {0.f, 0.f, 0.f, 0.f};
      acc2[i][j] = {0.f, 0.f, 0.f, 0.f};
    }

#pragma unroll
  for (int k = 0; k < 8; ++k) {
    const int q8 = k * 32 + kg * 8;
    const bf16x8 af0 = *(const bf16x8*)(S1b + (size_t)(wm + fr) * LQ + q8);
    const bf16x8 af1 = *(const bf16x8*)(S1b + (size_t)(wm + 16 + fr) * LQ + q8);
#pragma unroll
    for (int ni = 0; ni < 4; ++ni) {
      const int d = nt + wn + ni * 16 + fr;
      const bf16x8 b1 = *(const bf16x8*)(Qcb + (size_t)d * LQ + q8);
      const bf16x8 b2 = *(const bf16x8*)(Ub + (size_t)d * LQ + q8);
      acc1[0][ni] = mfma16(af0, b1, acc1[0][ni]);
      acc1[1][ni] = mfma16(af1, b1, acc1[1][ni]);
      acc2[0][ni] = mfma16(af0, b2, acc2[0][ni]);
      acc2[1][ni] = mfma16(af1, b2, acc2[1][ni]);
    }
  }

  // ---- epilogue: bounce acc1, write Ct/A/Ct*A (nt), then acc2 -> Ct*Bv ----
  const int r4 = kg * 4;
#pragma unroll
  for (int mi = 0; mi < 2; mi++)
#pragma unroll
    for (int ni = 0; ni < 4; ni++)
#pragma unroll
      for (int j = 0; j < 4; j++)
        bounce[wm + mi * 16 + r4 + j][wn + ni * 16 + fr] = acc1[mi][ni][j];
  __syncthreads();

  const size_t outB = (size_t)b * (4 * D_) * LC;
#pragma unroll
  for (int m = 0; m < 8; ++m) {
    const int dr = drb + m * 16;
    const int d = nt + dr;
    f32x4 av;
#pragma unroll
    for (int e = 0; e < 4; ++e) av[e] = bounce[cq + e][dr];
    const f32x4 cv = creg[m];
    f32x4 ca;
#pragma unroll
    for (int e = 0; e < 4; ++e) ca[e] = cv[e] * av[e];
    nt_store4(out + outB + (size_t)d * LC + c0 + cq, cv);                 // Ct
    nt_store4(out + outB + (size_t)(D_ + d) * LC + c0 + cq, av);          // A
    nt_store4(out + outB + (size_t)(2 * D_ + d) * LC + c0 + cq, ca);      // Ct*A
  }
  __syncthreads();
#pragma unroll
  for (int mi = 0; mi < 2; mi++)
#pragma unroll
    for (int ni = 0; ni < 4; ni++)
#pragma unroll
      for (int j = 0; j < 4; j++)
        bounce[wm + mi * 16 + r4 + j][wn + ni * 16 + fr] = acc2[mi][ni][j];
  __syncthreads();
#pragma unroll
  for (int m = 0; m < 8; ++m) {
    const int dr = drb + m * 16;
    const int d = nt + dr;
    f32x4 bv;
#pragma unroll
    for (int e = 0; e < 4; ++e) bv[e] = creg[m][e] * bounce[cq + e][dr];
    nt_store4(out + outB + (size_t)(3 * D_ + d) * LC + c0 + cq, bv);      // Ct*Bv
  }
}

// ---------------------------------------------------------------------------
extern "C" void kernel_launch(void* const* d_in, const int* in_sizes, int n_in,
                              void* d_out, int out_size, void* d_ws, size_t ws_size,
                              hipStream_t stream) {
  (void)in_sizes; (void)n_in; (void)out_size; (void)ws_size;
  const float* C = (const float*)d_in[0];
  const float* Q = (const float*)d_in[1];
  const float* cmask = (const float*)d_in[2];
  const float* qmask = (const float*)d_in[3];
  const float* w = (const float*)d_in[4];
  float* out = (float*)d_out;

  float* ws = (float*)d_ws;
  // Up region: 8-split bf16 slot layout = 8*32*4*16384 bf16 = 33.5 MB,
  // byte-identical extent to the old 4-split fp32 region.
  const size_t UPF = (size_t)4 * B_ * D_ * LQ;      // float-equivalents
  bf16* Up = (bf16*)ws;
  float* cpm = ws + UPF;                            // B*32*LQ
  float* cps = cpm + B_ * 32 * LQ;                  // B*32*LQ
  float* cscl = cps + B_ * 32 * LQ;                 // B*LQ
  float* bqp = cscl + B_ * LQ;                      // B*4*LQ
  bf16* S1b = (bf16*)(bqp + B_ * 4 * LQ);           // B*LC*LQ bf16 (33.5MB)
  bf16* S1tb = S1b + (size_t)B_ * LC * LQ;          // B*LQ*LC bf16 (33.5MB)
  bf16* Utb = S1tb + (size_t)B_ * LC * LQ;          // B*D_*LQ bf16 (4MB)
  bf16* Qb16 = Utb + (size_t)B_ * D_ * LQ;          // B*D_*LQ bf16 (4MB)
  bf16* Qtb = (bf16*)Up;  // overlay: Qtb dead before k3 writes Up (stream order)

  qprep<<<dim3(16, B_), 256, 0, stream>>>(Q, w, Qtb, Qb16, bqp);
  k1_sgemm<<<dim3(LC / 64, B_), 256, 0, stream>>>(C, Qtb, w, cmask, qmask, bqp,
                                                  S1b, S1tb, cpm, cps);
  k2_colstats<<<dim3(B_), 256, 0, stream>>>(cpm, cps, cscl);
  k3_ugemm<<<dim3(32 * B_), 256, 0, stream>>>(S1tb, C, Up);
  k3r_reduce<<<dim3(64 * B_), 256, 0, stream>>>(Up, cscl, Utb);
  k4_final<<<dim3(64 * B_), 256, 0, stream>>>(S1b, C, Qb16, Utb, out);
}

// Round 15
// 228.364 us; speedup vs baseline: 1.0212x; 1.0212x over previous
//
#include <hip/hip_runtime.h>

// CQAttention fused pipeline for MI355X (gfx950).
// B=32, D=256, Lc=2048, Lq=256, fp32 in/out, bf16 MFMA internally.
// R15 = exact restoration of R9/R13 (best measured: 228.4 / 228.8 us).
// Probes R10 (direct epilogue, -20), R11 (k4 occupancy, -8), R12 (k3
// qt-merge, -2), R14 (k3 KSPLIT=8 bf16 partials, -4) all regressed vs this
// configuration — it is the empirical optimum of the 6-kernel structure.
// Workspace ~105 MB.

#define B_ 32
#define D_ 256
#define LC 2048
#define LQ 256
#define KSPLIT 4
#define NEG_INF (-1e30f)

using bf16   = __bf16;
using bf16x4 = __attribute__((ext_vector_type(4))) __bf16;
using bf16x8 = __attribute__((ext_vector_type(8))) __bf16;
using f32x4  = __attribute__((ext_vector_type(4))) float;

static __device__ __forceinline__ f32x4 mfma16(bf16x8 a, bf16x8 b, f32x4 c) {
  return __builtin_amdgcn_mfma_f32_16x16x32_bf16(a, b, c, 0, 0, 0);
}
static __device__ __forceinline__ void nt_store4(float* p, f32x4 v) {
  __builtin_nontemporal_store(v, (f32x4*)p);
}

// ---------------------------------------------------------------------------
// K0a: transpose Q (b,d,q) f32 -> Qtb (b,q,d) bf16; cast Qb16[b][d][q];
// and per-(dt,q) partial dots bqp[b][dt][q] = sum_{d in dt} Q[d][q]*w2[d].
// ---------------------------------------------------------------------------
__global__ __launch_bounds__(256) void qprep(const float* __restrict__ Q,
                                             const float* __restrict__ w,
                                             bf16* __restrict__ Qtb,
                                             bf16* __restrict__ Qb16,
                                             float* __restrict__ bqp) {
  __shared__ float t[64][65];
  __shared__ float pb[4][64];
  const int b  = blockIdx.y;
  const int qt = (blockIdx.x >> 2) * 64;
  const int dtI = blockIdx.x & 3, dt = dtI * 64;
  const int c  = threadIdx.x & 63, r0 = threadIdx.x >> 6;
  const float* Qb = Q + (size_t)b * D_ * LQ;
  bf16* Qcb = Qb16 + (size_t)b * D_ * LQ;
  float partial = 0.f;
#pragma unroll
  for (int r = r0; r < 64; r += 4) {
    const float v = Qb[(size_t)(dt + r) * LQ + qt + c];
    t[r][c] = v;
    Qcb[(size_t)(dt + r) * LQ + qt + c] = (bf16)v;
    partial += v * w[D_ + dt + r];
  }
  pb[r0][c] = partial;
  __syncthreads();
  bf16* O = Qtb + (size_t)b * LQ * D_;
#pragma unroll
  for (int r = r0; r < 64; r += 4)
    O[(size_t)(qt + r) * D_ + dt + c] = (bf16)t[c][r];  // Qtb[q][d] = Q[d][q]
  if (r0 == 0)
    bqp[((size_t)(b * 4 + dtI)) * LQ + qt + c] = pb[0][c] + pb[1][c] + pb[2][c] + pb[3][c];
}

// ---------------------------------------------------------------------------
// K1: S = (C*w3)^T @ Q + a[c] + bq[q], rounded to bf16.
// R6 LDS staging + T14 register prefetch. S1 AND S1t written via LDS bounce.
// ---------------------------------------------------------------------------
__global__ __launch_bounds__(256) void k1_sgemm(
    const float* __restrict__ C, const bf16* __restrict__ Qtb,
    const float* __restrict__ w, const float* __restrict__ cmask,
    const float* __restrict__ qmask, const float* __restrict__ bqp,
    bf16* __restrict__ S1, bf16* __restrict__ S1t,
    float* __restrict__ cpmax, float* __restrict__ cpsum) {
  __shared__ union __align__(16) SmU {
    struct { bf16 As[64][72]; bf16 Bs[256][72]; } st;  // K-loop (46.1 KB)
    bf16 tb[256][72];                                   // S1t bounce
    bf16 sb[64][264];                                   // S1 bounce
  } smu;
  __shared__ float ared[4][64];
  __shared__ float wred[4][64];
  __shared__ float wsum[4][64];
  __shared__ float cml[64];
  __shared__ float qml[256];
  __shared__ float bql[256];

  const int b = blockIdx.y, ct = blockIdx.x, c0 = ct * 64;
  const int tid = threadIdx.x, lane = tid & 63, wv = tid >> 6;
  const float* Cb = C + (size_t)b * D_ * LC;
  const bf16* Qt = Qtb + (size_t)b * LQ * D_;
  const float* w1 = w;
  const float* w3 = w + 2 * D_;

  if (tid < 64) cml[tid] = cmask[b * LC + c0 + tid];
  qml[tid] = qmask[b * LQ + tid];
  bql[tid] = bqp[(size_t)(b * 4 + 0) * LQ + tid] + bqp[(size_t)(b * 4 + 1) * LQ + tid] +
             bqp[(size_t)(b * 4 + 2) * LQ + tid] + bqp[(size_t)(b * 4 + 3) * LQ + tid];

  f32x4 acc[4][4];
#pragma unroll
  for (int i = 0; i < 4; i++)
#pragma unroll
    for (int j = 0; j < 4; j++) acc[i][j] = {0.f, 0.f, 0.f, 0.f};
  float acc_a = 0.f;

  const int sm = tid & 63;   // staging: m (c)
  const int skg = tid >> 6;  // staging: k-group

  // ---- prologue: prefetch tile 0 into registers ----
  float aPre[16];
  bf16x8 bPre[8];
#pragma unroll
  for (int i = 0; i < 16; ++i)
    aPre[i] = Cb[(size_t)(skg * 16 + i) * LC + c0 + sm];
#pragma unroll
  for (int p = 0; p < 8; ++p) {
    const int idx = (p * 256 + tid) * 8;
    bPre[p] = *(const bf16x8*)(Qt + (size_t)(idx >> 6) * D_ + (idx & 63));
  }

  for (int it = 0; it < 4; ++it) {
    const int k0 = it * 64;
#pragma unroll
    for (int i = 0; i < 16; ++i) {
      const int k = skg * 16 + i, kgl = k0 + k;
      smu.st.As[sm][k] = (bf16)(aPre[i] * w3[kgl]);
      acc_a += aPre[i] * w1[kgl];
    }
#pragma unroll
    for (int p = 0; p < 8; ++p) {
      const int idx = (p * 256 + tid) * 8;
      *(bf16x8*)(&smu.st.Bs[idx >> 6][idx & 63]) = bPre[p];
    }
    __syncthreads();
    // T14: next tile's global loads issued now; complete under the MFMAs
    if (it < 3) {
#pragma unroll
      for (int i = 0; i < 16; ++i)
        aPre[i] = Cb[(size_t)(k0 + 64 + skg * 16 + i) * LC + c0 + sm];
#pragma unroll
      for (int p = 0; p < 8; ++p) {
        const int idx = (p * 256 + tid) * 8;
        bPre[p] = *(const bf16x8*)(Qt + (size_t)(idx >> 6) * D_ + k0 + 64 + (idx & 63));
      }
    }
#pragma unroll
    for (int kk = 0; kk < 64; kk += 32) {
      bf16x8 af[4], bfr[4];
#pragma unroll
      for (int mi = 0; mi < 4; mi++)
        af[mi] = *(const bf16x8*)(&smu.st.As[mi * 16 + (lane & 15)][kk + (lane >> 4) * 8]);
#pragma unroll
      for (int ni = 0; ni < 4; ni++)
        bfr[ni] = *(const bf16x8*)(&smu.st.Bs[wv * 64 + ni * 16 + (lane & 15)][kk + (lane >> 4) * 8]);
#pragma unroll
      for (int mi = 0; mi < 4; mi++)
#pragma unroll
        for (int ni = 0; ni < 4; ni++)
          acc[mi][ni] = mfma16(af[mi], bfr[ni], acc[mi][ni]);
    }
    __syncthreads();
  }

  ared[skg][sm] = acc_a;
  __syncthreads();

  const int r4 = (lane >> 4) * 4;  // fragment row base
  const int cn = lane & 15;        // fragment col

  // acc <- raw S rounded to bf16 (kept as floats of rounded values)
#pragma unroll
  for (int mi = 0; mi < 4; mi++)
#pragma unroll
    for (int j = 0; j < 4; j++) {
      const int m = mi * 16 + r4 + j;
      const float aval = ared[0][m] + ared[1][m] + ared[2][m] + ared[3][m];
#pragma unroll
      for (int ni = 0; ni < 4; ni++) {
        const int n = wv * 64 + ni * 16 + cn;
        const bf16 sb = (bf16)(acc[mi][ni][j] + aval + bql[n]);
        acc[mi][ni][j] = (float)sb;
      }
    }

  // ---- column partial stats (cmask logits, raw acc) ----
#pragma unroll
  for (int ni = 0; ni < 4; ni++) {
    const int n = wv * 64 + ni * 16 + cn;
    float mx = -3.0e38f;
#pragma unroll
    for (int mi = 0; mi < 4; mi++)
#pragma unroll
      for (int j = 0; j < 4; j++) {
        const int m = mi * 16 + r4 + j;
        const float cmv = cml[m];
        const float lg = acc[mi][ni][j] * cmv + (1.f - cmv) * NEG_INF;
        mx = fmaxf(mx, lg);
      }
    mx = fmaxf(mx, __shfl_xor(mx, 16));
    mx = fmaxf(mx, __shfl_xor(mx, 32));
    float ps = 0.f;
#pragma unroll
    for (int mi = 0; mi < 4; mi++)
#pragma unroll
      for (int j = 0; j < 4; j++) {
        const int m = mi * 16 + r4 + j;
        const float cmv = cml[m];
        const float lg = acc[mi][ni][j] * cmv + (1.f - cmv) * NEG_INF;
        ps += __expf(lg - mx);
      }
    ps += __shfl_xor(ps, 16);
    ps += __shfl_xor(ps, 32);
    if ((lane >> 4) == 0) {
      cpmax[((size_t)(b * 32 + ct)) * LQ + n] = mx;
      cpsum[((size_t)(b * 32 + ct)) * LQ + n] = ps;
    }
  }

  // ---- row max (qmask logits) ----
#pragma unroll
  for (int mi = 0; mi < 4; mi++)
#pragma unroll
    for (int j = 0; j < 4; j++) {
      float mx = -3.0e38f;
#pragma unroll
      for (int ni = 0; ni < 4; ni++) {
        const int n = wv * 64 + ni * 16 + cn;
        const float qm = qml[n];
        const float lg = acc[mi][ni][j] * qm + (1.f - qm) * NEG_INF;
        mx = fmaxf(mx, lg);
      }
      for (int s = 1; s < 16; s <<= 1) mx = fmaxf(mx, __shfl_xor(mx, s));
      if (cn == 0) wred[wv][mi * 16 + r4 + j] = mx;
    }
  __syncthreads();

  // ---- e = exp(lg - rm) overwrites acc; row sums ----
  float rmv[4][4];
#pragma unroll
  for (int mi = 0; mi < 4; mi++)
#pragma unroll
    for (int j = 0; j < 4; j++) {
      const int m = mi * 16 + r4 + j;
      const float rm = fmaxf(fmaxf(wred[0][m], wred[1][m]), fmaxf(wred[2][m], wred[3][m]));
      rmv[mi][j] = rm;
      float ps = 0.f;
#pragma unroll
      for (int ni = 0; ni < 4; ni++) {
        const int n = wv * 64 + ni * 16 + cn;
        const float qm = qml[n];
        const float lg = acc[mi][ni][j] * qm + (1.f - qm) * NEG_INF;
        const float e = __expf(lg - rm);
        acc[mi][ni][j] = e;
        ps += e;
      }
      for (int s = 1; s < 16; s <<= 1) ps += __shfl_xor(ps, s);
      if (cn == 0) wsum[wv][m] = ps;
    }
  __syncthreads();

  // ---- phase A: bounce S1t = bf16(e * cml * exp(rm)), flush coalesced ----
#pragma unroll
  for (int mi = 0; mi < 4; mi++)
#pragma unroll
    for (int j = 0; j < 4; j++) {
      const int m = mi * 16 + r4 + j;
      const float f = cml[m] * __expf(rmv[mi][j]);
#pragma unroll
      for (int ni = 0; ni < 4; ni++) {
        const int n = wv * 64 + ni * 16 + cn;
        smu.tb[n][m] = (bf16)(acc[mi][ni][j] * f);
      }
    }
  __syncthreads();
  {
    bf16* dst = S1t + ((size_t)b * LQ + tid) * LC + c0;
#pragma unroll
    for (int jj = 0; jj < 8; ++jj)
      *(bf16x8*)(dst + jj * 8) = *(const bf16x8*)(&smu.tb[tid][jj * 8]);
  }
  __syncthreads();

  // ---- phase B: bounce S1 = bf16(e * rsl), flush coalesced ----
#pragma unroll
  for (int mi = 0; mi < 4; mi++)
#pragma unroll
    for (int j = 0; j < 4; j++) {
      const int m = mi * 16 + r4 + j;
      const float rs = wsum[0][m] + wsum[1][m] + wsum[2][m] + wsum[3][m];
      const float rsl = 1.0f / rs;
#pragma unroll
      for (int ni = 0; ni < 4; ni++) {
        const int n = wv * 64 + ni * 16 + cn;
        smu.sb[m][n] = (bf16)(acc[mi][ni][j] * rsl);
      }
    }
  __syncthreads();
  {
    bf16* S1b = S1 + ((size_t)b * LC + c0) * LQ;
#pragma unroll
    for (int p = 0; p < 8; ++p) {
      const int flat = p * 2048 + tid * 8;
      *(bf16x8*)(S1b + flat) = *(const bf16x8*)(&smu.sb[flat >> 8][flat & 255]);
    }
  }
}

// ---------------------------------------------------------------------------
// K2: combine 32 column-partial stats -> cscl[b][q] = exp(-cmax)/csum.
// ---------------------------------------------------------------------------
__global__ __launch_bounds__(256) void k2_colstats(const float* __restrict__ cpmax,
                                                   const float* __restrict__ cpsum,
                                                   float* __restrict__ cscl) {
  const int b = blockIdx.x, q = threadIdx.x;
  float m = -3.0e38f;
  for (int t = 0; t < 32; t++) m = fmaxf(m, cpmax[(size_t)(b * 32 + t) * LQ + q]);
  float s = 0.f;
  for (int t = 0; t < 32; t++)
    s += cpsum[(size_t)(b * 32 + t) * LQ + q] * __expf(cpmax[(size_t)(b * 32 + t) * LQ + q] - m);
  cscl[b * LQ + q] = __expf(-m) / s;
}

// ---------------------------------------------------------------------------
// K3: Uraw[q,d] = sum_c S1t[q,c]*Ct[c,d] — split-K, pure-load register GEMM.
// Quad-XCD swizzle; Up written non-temporally.
// ---------------------------------------------------------------------------
__global__ __launch_bounds__(256, 3) void k3_ugemm(
    const bf16* __restrict__ S1t, const float* __restrict__ C,
    float* __restrict__ Up) {
  const int g = blockIdx.x;            // 0..511
  const int x = g & 7, s = g >> 3;     // s: 0..63
  const int quad = (s >> 2) * 8 + x;   // 0..127 : (b, ks)
  const int inner = s & 3;             // (qt, dtI)
  const int b = quad >> 2, ks = quad & 3;
  const int qt = inner >> 1, dtI = inner & 1;
  const int mt = qt * 128, nt = dtI * 128;
  const int cbase = ks * (LC / KSPLIT);

  const int tid = threadIdx.x, lane = tid & 63, wv = tid >> 6;
  const int wm = (wv >> 1) * 64, wn = (wv & 1) * 64;
  const int fr = lane & 15, kg = lane >> 4;

  const bf16* Sb = S1t + (size_t)b * LQ * LC;
  const float* Cb = C + (size_t)b * D_ * LC;

  int qrow[4];
#pragma unroll
  for (int mi = 0; mi < 4; mi++) qrow[mi] = mt + wm + mi * 16 + fr;

  f32x4 acc[4][4];
#pragma unroll
  for (int i = 0; i < 4; i++)
#pragma unroll
    for (int j = 0; j < 4; j++) acc[i][j] = {0.f, 0.f, 0.f, 0.f};

#pragma unroll 2
  for (int k0 = 0; k0 < LC / KSPLIT; k0 += 64) {
    const int c8 = cbase + k0 + kg * 8;
    bf16x8 af[4][2];
#pragma unroll
    for (int mi = 0; mi < 4; mi++)
#pragma unroll
      for (int s2 = 0; s2 < 2; ++s2)
        af[mi][s2] = *(const bf16x8*)(Sb + (size_t)qrow[mi] * LC + c8 + s2 * 32);
    bf16x8 bfr[4][2];
#pragma unroll
    for (int ni = 0; ni < 4; ni++) {
      const float* cp = Cb + (size_t)(nt + wn + ni * 16 + fr) * LC + c8;
#pragma unroll
      for (int s2 = 0; s2 < 2; ++s2) {
        const f32x4 v0 = *(const f32x4*)(cp + s2 * 32);
        const f32x4 v1 = *(const f32x4*)(cp + s2 * 32 + 4);
        bf16x8 tt;
#pragma unroll
        for (int e = 0; e < 4; ++e) { tt[e] = (bf16)v0[e]; tt[e + 4] = (bf16)v1[e]; }
        bfr[ni][s2] = tt;
      }
    }
#pragma unroll
    for (int s2 = 0; s2 < 2; ++s2)
#pragma unroll
      for (int mi = 0; mi < 4; mi++)
#pragma unroll
        for (int ni = 0; ni < 4; ni++)
          acc[mi][ni] = mfma16(af[mi][s2], bfr[ni][s2], acc[mi][ni]);
  }

  float* Ub = Up + ((size_t)(ks * B_ + b)) * D_ * LQ;
#pragma unroll
  for (int mi = 0; mi < 4; mi++)
#pragma unroll
    for (int ni = 0; ni < 4; ni++) {
      const int q = mt + wm + mi * 16 + kg * 4;
      const int d = nt + wn + ni * 16 + fr;
      nt_store4(Ub + (size_t)d * LQ + q, acc[mi][ni]);
    }
}

// ---------------------------------------------------------------------------
// K3r: Utb[b][d][q] = bf16( cscl[b][q] * sum_ks Up[ks][b][d][q] )
// ---------------------------------------------------------------------------
__global__ __launch_bounds__(256) void k3r_reduce(const float* __restrict__ Up,
                                                  const float* __restrict__ cscl,
                                                  bf16* __restrict__ Utb) {
  const size_t NP = (size_t)B_ * D_ * LQ;
  const size_t i4 = ((size_t)blockIdx.x * 256 + threadIdx.x) * 4;
  const int b = (int)(i4 >> 16);       // D_*LQ = 65536
  const int q = (int)(i4 & (LQ - 1));
  f32x4 s = __builtin_nontemporal_load((const f32x4*)(Up + i4));
#pragma unroll
  for (int p = 1; p < KSPLIT; ++p) {
    const f32x4 v = __builtin_nontemporal_load((const f32x4*)(Up + p * NP + i4));
    s[0] += v[0]; s[1] += v[1]; s[2] += v[2]; s[3] += v[3];
  }
  const f32x4 sc = *(const f32x4*)(cscl + b * LQ + q);
  bf16x4 o = {(bf16)(s[0] * sc[0]), (bf16)(s[1] * sc[1]),
              (bf16)(s[2] * sc[2]), (bf16)(s[3] * sc[3])};
  *(bf16x4*)(Utb + i4) = o;
}

// ---------------------------------------------------------------------------
// K4: A = S1 @ Qt, Bv = S1 @ U — k-outer register GEMM. Bounce epilogue
// (256B-contiguous stores per row), (256,3). Output non-temporal.
// ---------------------------------------------------------------------------
__global__ __launch_bounds__(256, 3) void k4_final(
    const bf16* __restrict__ S1, const float* __restrict__ C,
    const bf16* __restrict__ Qb16, const bf16* __restrict__ Utb,
    float* __restrict__ out) {
  __shared__ float bounce[64][131];

  const int g = blockIdx.x;            // 0..2047
  const int x = g & 7, s = g >> 3;     // s: 0..255
  const int t = s >> 1, ntI = s & 1;
  const int pair = t * 8 + x;          // 0..1023
  const int b = pair >> 5, ct = pair & 31;
  const int c0 = ct * 64, nt = ntI * 128;

  const int tid = threadIdx.x, lane = tid & 63, wv = tid >> 6;
  const int wm = (wv >> 1) * 32, wn = (wv & 1) * 64;
  const int fr = lane & 15, kg = lane >> 4;

  const bf16* S1b = S1 + ((size_t)b * LC + c0) * LQ;
  const float* Cb = C + (size_t)b * D_ * LC;
  const bf16* Qcb = Qb16 + (size_t)b * D_ * LQ;
  const bf16* Ub = Utb + (size_t)b * D_ * LQ;

  // ---- prefetch epilogue C tiles early (HBM latency under K-loop) ----
  const int cq = (tid & 15) * 4;    // 4 consecutive c per thread
  const int drb = tid >> 4;         // d-row base (0..15)
  f32x4 creg[8];
#pragma unroll
  for (int m = 0; m < 8; ++m)
    creg[m] = *(const f32x4*)(Cb + (size_t)(nt + drb + m * 16) * LC + c0 + cq);

  f32x4 acc1[2][4], acc2[2][4];
#pragma unroll
  for (int i = 0; i < 2; i++)
#pragma unroll
    for (int j = 0; j < 4; j++) {
      acc1[i][j] = {0.f, 0.f, 0.f, 0.f};
      acc2[i][j] = {0.f, 0.f, 0.f, 0.f};
    }

#pragma unroll
  for (int k = 0; k < 8; ++k) {
    const int q8 = k * 32 + kg * 8;
    const bf16x8 af0 = *(const bf16x8*)(S1b + (size_t)(wm + fr) * LQ + q8);
    const bf16x8 af1 = *(const bf16x8*)(S1b + (size_t)(wm + 16 + fr) * LQ + q8);
#pragma unroll
    for (int ni = 0; ni < 4; ++ni) {
      const int d = nt + wn + ni * 16 + fr;
      const bf16x8 b1 = *(const bf16x8*)(Qcb + (size_t)d * LQ + q8);
      const bf16x8 b2 = *(const bf16x8*)(Ub + (size_t)d * LQ + q8);
      acc1[0][ni] = mfma16(af0, b1, acc1[0][ni]);
      acc1[1][ni] = mfma16(af1, b1, acc1[1][ni]);
      acc2[0][ni] = mfma16(af0, b2, acc2[0][ni]);
      acc2[1][ni] = mfma16(af1, b2, acc2[1][ni]);
    }
  }

  // ---- epilogue: bounce acc1, write Ct/A/Ct*A (nt), then acc2 -> Ct*Bv ----
  const int r4 = kg * 4;
#pragma unroll
  for (int mi = 0; mi < 2; mi++)
#pragma unroll
    for (int ni = 0; ni < 4; ni++)
#pragma unroll
      for (int j = 0; j < 4; j++)
        bounce[wm + mi * 16 + r4 + j][wn + ni * 16 + fr] = acc1[mi][ni][j];
  __syncthreads();

  const size_t outB = (size_t)b * (4 * D_) * LC;
#pragma unroll
  for (int m = 0; m < 8; ++m) {
    const int dr = drb + m * 16;
    const int d = nt + dr;
    f32x4 av;
#pragma unroll
    for (int e = 0; e < 4; ++e) av[e] = bounce[cq + e][dr];
    const f32x4 cv = creg[m];
    f32x4 ca;
#pragma unroll
    for (int e = 0; e < 4; ++e) ca[e] = cv[e] * av[e];
    nt_store4(out + outB + (size_t)d * LC + c0 + cq, cv);                 // Ct
    nt_store4(out + outB + (size_t)(D_ + d) * LC + c0 + cq, av);          // A
    nt_store4(out + outB + (size_t)(2 * D_ + d) * LC + c0 + cq, ca);      // Ct*A
  }
  __syncthreads();
#pragma unroll
  for (int mi = 0; mi < 2; mi++)
#pragma unroll
    for (int ni = 0; ni < 4; ni++)
#pragma unroll
      for (int j = 0; j < 4; j++)
        bounce[wm + mi * 16 + r4 + j][wn + ni * 16 + fr] = acc2[mi][ni][j];
  __syncthreads();
#pragma unroll
  for (int m = 0; m < 8; ++m) {
    const int dr = drb + m * 16;
    const int d = nt + dr;
    f32x4 bv;
#pragma unroll
    for (int e = 0; e < 4; ++e) bv[e] = creg[m][e] * bounce[cq + e][dr];
    nt_store4(out + outB + (size_t)(3 * D_ + d) * LC + c0 + cq, bv);      // Ct*Bv
  }
}

// ---------------------------------------------------------------------------
extern "C" void kernel_launch(void* const* d_in, const int* in_sizes, int n_in,
                              void* d_out, int out_size, void* d_ws, size_t ws_size,
                              hipStream_t stream) {
  (void)in_sizes; (void)n_in; (void)out_size; (void)ws_size;
  const float* C = (const float*)d_in[0];
  const float* Q = (const float*)d_in[1];
  const float* cmask = (const float*)d_in[2];
  const float* qmask = (const float*)d_in[3];
  const float* w = (const float*)d_in[4];
  float* out = (float*)d_out;

  float* ws = (float*)d_ws;
  float* Up = ws;                                   // KSPLIT*B*D*LQ fp32 (33.5MB)
  float* cpm = Up + (size_t)KSPLIT * B_ * D_ * LQ;  // B*32*LQ
  float* cps = cpm + B_ * 32 * LQ;                  // B*32*LQ
  float* cscl = cps + B_ * 32 * LQ;                 // B*LQ
  float* bqp = cscl + B_ * LQ;                      // B*4*LQ
  bf16* S1b = (bf16*)(bqp + B_ * 4 * LQ);           // B*LC*LQ bf16 (33.5MB)
  bf16* S1tb = S1b + (size_t)B_ * LC * LQ;          // B*LQ*LC bf16 (33.5MB)
  bf16* Utb = S1tb + (size_t)B_ * LC * LQ;          // B*D_*LQ bf16 (4MB)
  bf16* Qb16 = Utb + (size_t)B_ * D_ * LQ;          // B*D_*LQ bf16 (4MB)
  bf16* Qtb = (bf16*)Up;  // overlay: Qtb dead before k3 writes Up (stream order)

  qprep<<<dim3(16, B_), 256, 0, stream>>>(Q, w, Qtb, Qb16, bqp);
  k1_sgemm<<<dim3(LC / 64, B_), 256, 0, stream>>>(C, Qtb, w, cmask, qmask, bqp,
                                                  S1b, S1tb, cpm, cps);
  k2_colstats<<<dim3(B_), 256, 0, stream>>>(cpm, cps, cscl);
  k3_ugemm<<<dim3(16 * B_), 256, 0, stream>>>(S1tb, C, Up);
  k3r_reduce<<<dim3((B_ * D_ * LQ) / 1024), 256, 0, stream>>>(Up, cscl, Utb);
  k4_final<<<dim3(64 * B_), 256, 0, stream>>>(S1b, C, Qb16, Utb, out);
}